// Round 1
// baseline (255.652 us; speedup 1.0000x reference)
//
#include <hip/hip_runtime.h>
#include <hip/hip_bf16.h>

#define TEMP_INV 10.0f

// One block per batch row. 256 threads.
// out[b, idx] = prod_f bins[b,f,digit_f(idx)], idx = i0*4^6 + ... + i6.
// Factorized: prodHi[i0i1i2] * prodMid[i3i4i5] * v6[i6].
__global__ __launch_bounds__(256) void dtree_kernel(
    const float* __restrict__ x,        // (B, 7)
    const float* __restrict__ cut,      // (7, 3)
    float* __restrict__ out)            // (B, 16384)
{
    const int b = blockIdx.x;
    const int t = threadIdx.x;

    __shared__ float sb[7][4];      // per-feature softmax bins
    __shared__ float prodHi[64];    // features 0..2
    __shared__ float prodMid[64];   // features 3..5

    if (t < 7) {
        // sort the 3 cutpoints of feature t ascending (min/max network)
        float c0 = cut[t * 3 + 0];
        float c1 = cut[t * 3 + 1];
        float c2 = cut[t * 3 + 2];
        float lo = fminf(c0, c1), hi = fmaxf(c0, c1);
        float m0 = fminf(lo, c2);
        float m2 = fmaxf(hi, c2);
        float m1 = (c0 + c1 + c2) - m0 - m2;

        float xb = x[(size_t)b * 7 + t];
        // h_i = x*W_i + b_i ; W=[1,2,3,4], b = [0, -m0, -m0-m1, -m0-m1-m2]
        float h0 = xb;
        float h1 = xb * 2.0f - m0;
        float h2 = xb * 3.0f - (m0 + m1);
        float h3 = xb * 4.0f - (m0 + m1 + m2);
        h0 *= TEMP_INV; h1 *= TEMP_INV; h2 *= TEMP_INV; h3 *= TEMP_INV;
        float mx = fmaxf(fmaxf(h0, h1), fmaxf(h2, h3));
        float e0 = __expf(h0 - mx);
        float e1 = __expf(h1 - mx);
        float e2 = __expf(h2 - mx);
        float e3 = __expf(h3 - mx);
        float inv = 1.0f / (e0 + e1 + e2 + e3);
        sb[t][0] = e0 * inv;
        sb[t][1] = e1 * inv;
        sb[t][2] = e2 * inv;
        sb[t][3] = e3 * inv;
    }
    __syncthreads();

    if (t < 64) {
        prodHi[t] = sb[0][(t >> 4) & 3] * sb[1][(t >> 2) & 3] * sb[2][t & 3];
    } else if (t < 128) {
        int k = t - 64;
        prodMid[k] = sb[3][(k >> 4) & 3] * sb[4][(k >> 2) & 3] * sb[5][k & 3];
    }
    __syncthreads();

    const float4 v6 = make_float4(sb[6][0], sb[6][1], sb[6][2], sb[6][3]);
    float4* __restrict__ o = (float4*)(out + (size_t)b * 16384);

#pragma unroll
    for (int j = 0; j < 16; ++j) {
        int n = j * 256 + t;                 // float4 index within row, [0,4096)
        float P = prodHi[n >> 6] * prodMid[n & 63];
        o[n] = make_float4(P * v6.x, P * v6.y, P * v6.z, P * v6.w);
    }
}

extern "C" void kernel_launch(void* const* d_in, const int* in_sizes, int n_in,
                              void* d_out, int out_size, void* d_ws, size_t ws_size,
                              hipStream_t stream) {
    const float* x   = (const float*)d_in[0];
    const float* cut = (const float*)d_in[1];
    float* out = (float*)d_out;
    const int B = in_sizes[0] / 7;   // 4096
    dtree_kernel<<<B, 256, 0, stream>>>(x, cut, out);
}